// Round 15
// baseline (752.470 us; speedup 1.0000x reference)
//
#include <hip/hip_runtime.h>

// Conv2d 3x3 SAME, stride 1: x (16,64,256,256) f32, w (128,64,3,3), bias (128) -> out (16,128,256,256)
//
// V16 = V15 minus the esc LDS round trip: DIRECT cached output stores.
//  V8's direct stores regressed because they were NONTEMPORAL (64B half-lines can't merge
//  -> ~2x HBM write traffic). With V15's cached stores, the two cgf 64B halves of each
//  128B line merge in L2; HBM sees full-line writebacks. So esc (16 ds_write_b128 +
//  16 ds_read_b128 per lane per iter ~ 3.1k cyc/CU/iter on the binding LDS pipe,
//  + 34.8 KB LDS) is pure overhead -> removed.
//  acc[rr][cgf] = 4 consecutive px of cout wvid*16+ln -> one dwordx4 store each.
//  Everything else V15-verbatim: fused f32->f16 staging (both-sides swizzle), 10-slot
//  ring, XCD strip co-location, swapped mfma(bt,af,acc) D row=pixel, epilogue after
//  barrier, raw s_barrier + lgkmcnt(0) only, cached stores (L2-ack, async writeback).

typedef _Float16 half8_t __attribute__((ext_vector_type(8)));
typedef float floatx4 __attribute__((ext_vector_type(4)));

#define HH 256
#define WW 256
#define CIN 64
#define COUT 128
#define NB 16

#define ROW_LDS 8448              // bytes per LDS tile row (66 cols * 128 B)
#define NSLOT   10

// ---------- pass 1a: weights OIHW f32 -> w_t[9][8][128][8] f16 ----------
__global__ void Conv2d_wprep_kernel(const float* __restrict__ w, _Float16* __restrict__ w_t) {
    int idx = blockIdx.x * 256 + threadIdx.x;
    if (idx >= 9 * 8 * 128 * 8) return;
    const int j = idx & 7, cout = (idx >> 3) & 127, s = (idx >> 10) & 7, t = idx >> 13;
    w_t[idx] = (_Float16)w[(cout * 64 + s * 8 + j) * 9 + t];
}

// ---------- fused conv ----------
__global__ __launch_bounds__(512, 2) void Conv2dManual_77695958385099_kernel(
    const float* __restrict__ x, const _Float16* __restrict__ w_t,
    const float* __restrict__ bias, float* __restrict__ out) {
    __shared__ __align__(16) unsigned char xs[NSLOT * ROW_LDS];  // 84480 B
    const int tid = threadIdx.x;
    const int l = tid & 63, wvid = tid >> 6;    // wave -> couts wvid*16..+15
    const int g = l >> 4, ln = l & 15;

    // ---- XCD co-location decode: strips of one (band,n) share blockid mod 8 ----
    const int blin = blockIdx.x;                // 0..255
    const int g8 = blin & 7;
    const int r = blin >> 3;
    const int strip = r & 3;
    const int ghi = r >> 2;
    const int group = g8 + 8 * ghi;             // 0..63
    const int band = group & 3;
    const int n = group >> 2;

    const int ow0 = strip * 64;
    const int P0 = band * 64;

    // staging roles: 4 row-groups of 128 threads
    const int rw = tid >> 7;
    const int t7 = tid & 127;
    const int su = t7 & 7;                      // ci-unit (8 ci)
    const int cb = t7 >> 3;                     // col block 0..15 (4 cols each)
    const bool isEdge = (t7 >= 120);            // 8 lanes/row-group handle halo cols
    const int eu = t7 - 120;

    // ---- persistent weights: A[h][tap], 18 x half8 = 72 VGPR ----
    const char* wl = (const char*)w_t + g * 2048 + (wvid * 16 + ln) * 16;
    half8_t A[2][9];
#pragma unroll
    for (int h = 0; h < 2; ++h)
#pragma unroll
        for (int tp = 0; tp < 9; ++tp)
            A[h][tp] = *(const half8_t*)(wl + h * 8192 + tp * 16384);

    const float bv = bias[wvid * 16 + ln];

    // ---- per-lane LDS byte offsets: F[cgf][kx][h] (verified formula) ----
    int F[4][3][2];
#pragma unroll
    for (int cgf = 0; cgf < 4; ++cgf)
#pragma unroll
        for (int kx = 0; kx < 3; ++kx)
#pragma unroll
            for (int h = 0; h < 2; ++h) {
                const int c = cgf * 16 + kx + ln;
                F[cgf][kx][h] = c * 128 + (((4 * h + g) ^ (c & 7)) << 4);
            }

    // ---- staging helpers (edge loaded EARLY with main) ----
    auto stage_load = [&](int pr, float4 (&ld)[8], float (&e0)[8], float (&e1)[8]) {
        const int gr = pr - 1;
        const bool vrow = ((unsigned)gr < 256u);
        if (vrow) {
            const float4* xr = (const float4*)x +
                               (((size_t)(n * 64 + su * 8)) << 14) +
                               (size_t)gr * 64 + (ow0 >> 2) + cb;
#pragma unroll
            for (int j = 0; j < 8; ++j) ld[j] = xr[(size_t)j << 14];
        } else {
#pragma unroll
            for (int j = 0; j < 8; ++j) ld[j] = (float4){0.f, 0.f, 0.f, 0.f};
        }
        if (isEdge) {
            const float* xe = x + (((size_t)(n * 64 + eu * 8)) << 16) + (size_t)gr * 256;
#pragma unroll
            for (int j = 0; j < 8; ++j) {
                e0[j] = (vrow && ow0 > 0)        ? xe[((size_t)j << 16) + ow0 - 1]  : 0.f;
                e1[j] = (vrow && ow0 + 64 < 256) ? xe[((size_t)j << 16) + ow0 + 64] : 0.f;
            }
        }
    };
    auto stage_write = [&](int pr, const float4 (&ld)[8], const float (&e0)[8],
                           const float (&e1)[8]) {
        const unsigned sb = (unsigned)(pr % NSLOT) * ROW_LDS;
#pragma unroll
        for (int k = 0; k < 4; ++k) {
            const int c = 1 + cb * 4 + k;
            half8_t hv;
#pragma unroll
            for (int j = 0; j < 8; ++j) hv[j] = (_Float16)((const float*)&ld[j])[k];
            *(half8_t*)(xs + sb + c * 128 + ((su ^ (c & 7)) << 4)) = hv;
        }
        if (isEdge) {
            half8_t h0, h1;
#pragma unroll
            for (int j = 0; j < 8; ++j) {
                h0[j] = (_Float16)e0[j];
                h1[j] = (_Float16)e1[j];
            }
            *(half8_t*)(xs + sb + (eu << 4)) = h0;                      // c = 0
            *(half8_t*)(xs + sb + 65 * 128 + ((eu ^ 1) << 4)) = h1;     // c = 65
        }
    };

    // ---- prologue: stage padded rows P0..P0+5 ----
    {
        float4 ld[8]; float e0[8], e1[8];
        stage_load(P0 + rw, ld, e0, e1);
        stage_write(P0 + rw, ld, e0, e1);
        if (rw < 2) {
            stage_load(P0 + 4 + rw, ld, e0, e1);
            stage_write(P0 + 4 + rw, ld, e0, e1);
        }
    }
    asm volatile("s_waitcnt lgkmcnt(0)" ::: "memory");
    __builtin_amdgcn_s_barrier();
    __builtin_amdgcn_sched_barrier(0);

    int s0 = P0 % NSLOT;
#pragma unroll 1
    for (int it = 0; it < 16; ++it) {
        // ---- EARLY: issue next-tile f32 loads, hold in regs across compute (T14) ----
        float4 ld[8]; float e0[8], e1[8];
        const int prn = P0 + it * 4 + 6 + rw;
        if (it < 15) stage_load(prn, ld, e0, e1);
        __builtin_amdgcn_sched_barrier(0);

        int roff[6];
#pragma unroll
        for (int tt = 0; tt < 6; ++tt) {
            int st = s0 + tt;
            if (st >= NSLOT) st -= NSLOT;
            roff[tt] = st * ROW_LDS;
        }

        floatx4 acc[4][4];
#pragma unroll
        for (int rr = 0; rr < 4; ++rr)
#pragma unroll
            for (int cgf = 0; cgf < 4; ++cgf) acc[rr][cgf] = (floatx4){bv, bv, bv, bv};

        // ---- compute (simple, compiler-scheduled) ----
#pragma unroll
        for (int kx = 0; kx < 3; ++kx)
#pragma unroll
            for (int h = 0; h < 2; ++h)
#pragma unroll
                for (int cgf = 0; cgf < 4; ++cgf) {
                    const unsigned char* bp = xs + F[cgf][kx][h];
                    half8_t bt[6];
#pragma unroll
                    for (int tt = 0; tt < 6; ++tt)
                        bt[tt] = *(const half8_t*)(bp + roff[tt]);
#pragma unroll
                    for (int ky = 0; ky < 3; ++ky) {
                        const half8_t af = A[h][ky * 3 + kx];
#pragma unroll
                        for (int rr = 0; rr < 4; ++rr)
                            acc[rr][cgf] = __builtin_amdgcn_mfma_f32_16x16x32_f16(
                                bt[rr + ky], af, acc[rr][cgf], 0, 0, 0);  // D row=pixel
                    }
                }

        // ---- stage_write + barrier FIRST (epilogue off the barrier path) ----
        if (it < 15) {
            stage_write(prn, ld, e0, e1);
            asm volatile("s_waitcnt lgkmcnt(0)" ::: "memory");
            __builtin_amdgcn_s_barrier();
            __builtin_amdgcn_sched_barrier(0);
        }

        // ---- epilogue AFTER barrier: DIRECT cached dwordx4 stores.
        //      acc[rr][cgf] = 4 consecutive px for cout wvid*16+ln; the two cgf 64B
        //      halves of each 128B line merge in L2 (cached, write-allocate). ----
        float* obase = out + ((size_t)(n * 128 + wvid * 16 + ln)) * 65536 +
                       (size_t)(P0 + it * 4) * 256 + ow0 + g * 4;
#pragma unroll
        for (int rr = 0; rr < 4; ++rr)
#pragma unroll
            for (int cgf = 0; cgf < 4; ++cgf)
                *(floatx4*)(obase + rr * 256 + cgf * 16) = acc[rr][cgf];

        s0 += 4;
        if (s0 >= NSLOT) s0 -= NSLOT;
    }
}

// ---------- fallback (proven V2 fp32) if workspace too small ----------
__global__ __launch_bounds__(256) void Conv2d_fallback_kernel(
    const float* __restrict__ x, const float* __restrict__ w,
    const float* __restrict__ bias, float* __restrict__ out) {
    const int tx = threadIdx.x & 15, ty = threadIdx.x >> 4;
    const int ow0 = blockIdx.x * 64 + tx * 4;
    const int oh = blockIdx.y * 16 + ty;
    const int gg = blockIdx.z & 7, n = blockIdx.z >> 3;
    const int co = gg * 16;
    float acc[16][4];
#pragma unroll
    for (int c = 0; c < 16; ++c) {
        const float b = bias[co + c];
#pragma unroll
        for (int p = 0; p < 4; ++p) acc[c][p] = b;
    }
    const float* xn = x + (size_t)n * CIN * HH * WW;
    const float* wb = w + (size_t)co * CIN * 9;
    for (int ci = 0; ci < CIN; ++ci) {
        const float* xc = xn + (size_t)ci * HH * WW;
        float in[3][6];
#pragma unroll
        for (int ky = 0; ky < 3; ++ky) {
            const int iy = oh + ky - 1;
            if ((unsigned)iy < (unsigned)HH) {
                const float* row = xc + iy * WW;
                const float4 v = *(const float4*)(row + ow0);
                in[ky][1] = v.x; in[ky][2] = v.y; in[ky][3] = v.z; in[ky][4] = v.w;
                in[ky][0] = (ow0 > 0) ? row[ow0 - 1] : 0.0f;
                in[ky][5] = (ow0 < WW - 4) ? row[ow0 + 4] : 0.0f;
            } else {
#pragma unroll
                for (int j = 0; j < 6; ++j) in[ky][j] = 0.0f;
            }
        }
        const float* wc2 = wb + ci * 9;
#pragma unroll
        for (int c = 0; c < 16; ++c) {
            const float* wcc = wc2 + (size_t)c * CIN * 9;
#pragma unroll
            for (int ky = 0; ky < 3; ++ky)
#pragma unroll
                for (int kx = 0; kx < 3; ++kx) {
                    const float wv2 = wcc[ky * 3 + kx];
#pragma unroll
                    for (int p = 0; p < 4; ++p) acc[c][p] += in[ky][kx + p] * wv2;
                }
        }
    }
    const size_t hw = (size_t)HH * WW;
    float* ob = out + ((size_t)n * COUT + co) * hw + (size_t)oh * WW + ow0;
#pragma unroll
    for (int c = 0; c < 16; ++c) {
        float4 v;
        v.x = acc[c][0]; v.y = acc[c][1]; v.z = acc[c][2]; v.w = acc[c][3];
        *(float4*)(ob + (size_t)c * hw) = v;
    }
}

extern "C" void kernel_launch(void* const* d_in, const int* in_sizes, int n_in,
                              void* d_out, int out_size, void* d_ws, size_t ws_size,
                              hipStream_t stream) {
    const float* x = (const float*)d_in[0];
    const float* w = (const float*)d_in[1];
    const float* b = (const float*)d_in[2];
    float* out = (float*)d_out;

    const size_t wt_bytes = (size_t)9 * 8 * 128 * 8 * 2;      // 144 KiB

    if (ws_size >= wt_bytes) {
        _Float16* w_t = (_Float16*)d_ws;
        Conv2d_wprep_kernel<<<dim3(288), 256, 0, stream>>>(w, w_t);
        Conv2dManual_77695958385099_kernel<<<dim3(256), 512, 0, stream>>>(
            x, w_t, b, out);
    } else {
        dim3 grid(WW / 64, HH / 16, NB * (COUT / 16));
        Conv2d_fallback_kernel<<<grid, 256, 0, stream>>>(x, w, b, out);
    }
}

// Round 16
// 731.279 us; speedup vs baseline: 1.0290x; 1.0290x over previous
//
#include <hip/hip_runtime.h>

// Conv2d 3x3 SAME, stride 1: x (16,64,256,256) f32, w (128,64,3,3), bias (128) -> out (16,128,256,256)
//
// V17 = V15 (best, 731us) + amdgpu_waves_per_eu(2,2) — single-change A/B.
//  Mechanism: V12's profile proved the compiler clamps this kernel family to 128 VGPR
//  (targeting 4 waves/EU) and silently remats the A-fragment loads into the loop. But
//  occupancy here is LDS-bound at 1 block/CU (84.5 KB) = 2 waves/EU regardless, so the
//  clamp buys nothing and costs per-iter A-refetch from L2. Pinning waves_per_eu(2,2)
//  lets the allocator use ~220 regs and keep A[2][9] (72 VGPR) truly resident.
//  (V13 bundled this pin with manual pipeline macros + edge-late staging and regressed;
//  the pin was never isolated.)
//  Everything else V15-verbatim: fused f32->f16 staging (both-sides swizzle), 10-slot
//  ring, XCD strip co-location, swapped mfma(bt,af,acc) D row=pixel, esc b128 transpose
//  -> CACHED full-128B-line dwordx4 stores (L2-ack, async writeback), epilogue after
//  barrier, raw s_barrier + lgkmcnt(0) only.

typedef _Float16 half8_t __attribute__((ext_vector_type(8)));
typedef float floatx4 __attribute__((ext_vector_type(4)));

#define HH 256
#define WW 256
#define CIN 64
#define COUT 128
#define NB 16

#define ROW_LDS 8448              // bytes per LDS tile row (66 cols * 128 B)
#define NSLOT   10

// ---------- pass 1a: weights OIHW f32 -> w_t[9][8][128][8] f16 ----------
__global__ void Conv2d_wprep_kernel(const float* __restrict__ w, _Float16* __restrict__ w_t) {
    int idx = blockIdx.x * 256 + threadIdx.x;
    if (idx >= 9 * 8 * 128 * 8) return;
    const int j = idx & 7, cout = (idx >> 3) & 127, s = (idx >> 10) & 7, t = idx >> 13;
    w_t[idx] = (_Float16)w[(cout * 64 + s * 8 + j) * 9 + t];
}

// ---------- fused conv ----------
__global__ __launch_bounds__(512)
__attribute__((amdgpu_waves_per_eu(2, 2)))
void Conv2dManual_77695958385099_kernel(
    const float* __restrict__ x, const _Float16* __restrict__ w_t,
    const float* __restrict__ bias, float* __restrict__ out) {
    __shared__ __align__(16) unsigned char xs[NSLOT * ROW_LDS];  // 84480 B
    __shared__ __align__(16) float esc[8][1088];                 // 34816 B
    const int tid = threadIdx.x;
    const int l = tid & 63, wvid = tid >> 6;    // wave -> couts wvid*16..+15
    const int g = l >> 4, ln = l & 15;

    // ---- XCD co-location decode: strips of one (band,n) share blockid mod 8 ----
    const int blin = blockIdx.x;                // 0..255
    const int g8 = blin & 7;
    const int r = blin >> 3;
    const int strip = r & 3;
    const int ghi = r >> 2;
    const int group = g8 + 8 * ghi;             // 0..63
    const int band = group & 3;
    const int n = group >> 2;

    const int ow0 = strip * 64;
    const int P0 = band * 64;

    // staging roles: 4 row-groups of 128 threads
    const int rw = tid >> 7;
    const int t7 = tid & 127;
    const int su = t7 & 7;                      // ci-unit (8 ci)
    const int cb = t7 >> 3;                     // col block 0..15 (4 cols each)
    const bool isEdge = (t7 >= 120);            // 8 lanes/row-group handle halo cols
    const int eu = t7 - 120;

    // ---- persistent weights: A[h][tap], 18 x half8 = 72 VGPR ----
    const char* wl = (const char*)w_t + g * 2048 + (wvid * 16 + ln) * 16;
    half8_t A[2][9];
#pragma unroll
    for (int h = 0; h < 2; ++h)
#pragma unroll
        for (int tp = 0; tp < 9; ++tp)
            A[h][tp] = *(const half8_t*)(wl + h * 8192 + tp * 16384);

    const float bv = bias[wvid * 16 + ln];

    // ---- per-lane LDS byte offsets: F[cgf][kx][h] (verified formula) ----
    int F[4][3][2];
#pragma unroll
    for (int cgf = 0; cgf < 4; ++cgf)
#pragma unroll
        for (int kx = 0; kx < 3; ++kx)
#pragma unroll
            for (int h = 0; h < 2; ++h) {
                const int c = cgf * 16 + kx + ln;
                F[cgf][kx][h] = c * 128 + (((4 * h + g) ^ (c & 7)) << 4);
            }

    // ---- staging helpers (edge loaded EARLY with main) ----
    auto stage_load = [&](int pr, float4 (&ld)[8], float (&e0)[8], float (&e1)[8]) {
        const int gr = pr - 1;
        const bool vrow = ((unsigned)gr < 256u);
        if (vrow) {
            const float4* xr = (const float4*)x +
                               (((size_t)(n * 64 + su * 8)) << 14) +
                               (size_t)gr * 64 + (ow0 >> 2) + cb;
#pragma unroll
            for (int j = 0; j < 8; ++j) ld[j] = xr[(size_t)j << 14];
        } else {
#pragma unroll
            for (int j = 0; j < 8; ++j) ld[j] = (float4){0.f, 0.f, 0.f, 0.f};
        }
        if (isEdge) {
            const float* xe = x + (((size_t)(n * 64 + eu * 8)) << 16) + (size_t)gr * 256;
#pragma unroll
            for (int j = 0; j < 8; ++j) {
                e0[j] = (vrow && ow0 > 0)        ? xe[((size_t)j << 16) + ow0 - 1]  : 0.f;
                e1[j] = (vrow && ow0 + 64 < 256) ? xe[((size_t)j << 16) + ow0 + 64] : 0.f;
            }
        }
    };
    auto stage_write = [&](int pr, const float4 (&ld)[8], const float (&e0)[8],
                           const float (&e1)[8]) {
        const unsigned sb = (unsigned)(pr % NSLOT) * ROW_LDS;
#pragma unroll
        for (int k = 0; k < 4; ++k) {
            const int c = 1 + cb * 4 + k;
            half8_t hv;
#pragma unroll
            for (int j = 0; j < 8; ++j) hv[j] = (_Float16)((const float*)&ld[j])[k];
            *(half8_t*)(xs + sb + c * 128 + ((su ^ (c & 7)) << 4)) = hv;
        }
        if (isEdge) {
            half8_t h0, h1;
#pragma unroll
            for (int j = 0; j < 8; ++j) {
                h0[j] = (_Float16)e0[j];
                h1[j] = (_Float16)e1[j];
            }
            *(half8_t*)(xs + sb + (eu << 4)) = h0;                      // c = 0
            *(half8_t*)(xs + sb + 65 * 128 + ((eu ^ 1) << 4)) = h1;     // c = 65
        }
    };

    // ---- prologue: stage padded rows P0..P0+5 ----
    {
        float4 ld[8]; float e0[8], e1[8];
        stage_load(P0 + rw, ld, e0, e1);
        stage_write(P0 + rw, ld, e0, e1);
        if (rw < 2) {
            stage_load(P0 + 4 + rw, ld, e0, e1);
            stage_write(P0 + 4 + rw, ld, e0, e1);
        }
    }
    asm volatile("s_waitcnt lgkmcnt(0)" ::: "memory");
    __builtin_amdgcn_s_barrier();
    __builtin_amdgcn_sched_barrier(0);

    int s0 = P0 % NSLOT;
#pragma unroll 1
    for (int it = 0; it < 16; ++it) {
        // ---- EARLY: issue next-tile f32 loads, hold in regs across compute (T14) ----
        float4 ld[8]; float e0[8], e1[8];
        const int prn = P0 + it * 4 + 6 + rw;
        if (it < 15) stage_load(prn, ld, e0, e1);
        __builtin_amdgcn_sched_barrier(0);

        int roff[6];
#pragma unroll
        for (int tt = 0; tt < 6; ++tt) {
            int st = s0 + tt;
            if (st >= NSLOT) st -= NSLOT;
            roff[tt] = st * ROW_LDS;
        }

        floatx4 acc[4][4];
#pragma unroll
        for (int rr = 0; rr < 4; ++rr)
#pragma unroll
            for (int cgf = 0; cgf < 4; ++cgf) acc[rr][cgf] = (floatx4){bv, bv, bv, bv};

        // ---- compute (simple, compiler-scheduled) ----
#pragma unroll
        for (int kx = 0; kx < 3; ++kx)
#pragma unroll
            for (int h = 0; h < 2; ++h)
#pragma unroll
                for (int cgf = 0; cgf < 4; ++cgf) {
                    const unsigned char* bp = xs + F[cgf][kx][h];
                    half8_t bt[6];
#pragma unroll
                    for (int tt = 0; tt < 6; ++tt)
                        bt[tt] = *(const half8_t*)(bp + roff[tt]);
#pragma unroll
                    for (int ky = 0; ky < 3; ++ky) {
                        const half8_t af = A[h][ky * 3 + kx];
#pragma unroll
                        for (int rr = 0; rr < 4; ++rr)
                            acc[rr][cgf] = __builtin_amdgcn_mfma_f32_16x16x32_f16(
                                bt[rr + ky], af, acc[rr][cgf], 0, 0, 0);  // D row=pixel
                    }
                }

        // ---- stage_write + barrier FIRST (epilogue off the barrier path) ----
        if (it < 15) {
            stage_write(prn, ld, e0, e1);
            asm volatile("s_waitcnt lgkmcnt(0)" ::: "memory");
            __builtin_amdgcn_s_barrier();
            __builtin_amdgcn_sched_barrier(0);
        }

        // ---- epilogue AFTER barrier: esc transpose -> CACHED full-line stores ----
        float* scr = &esc[wvid][0];
        float* obase = out + ((size_t)(n * 128 + wvid * 16)) * 65536 +
                       (size_t)(P0 + it * 4) * 256 + ow0;
#pragma unroll
        for (int rr = 0; rr < 4; ++rr) {
#pragma unroll
            for (int cgf = 0; cgf < 4; ++cgf)
                *(floatx4*)(scr + ln * 68 + cgf * 16 + g * 4) = acc[rr][cgf];
#pragma unroll
            for (int q = 0; q < 4; ++q) {
                const int co = q * 4 + g;
                const floatx4 v = *(const floatx4*)(scr + co * 68 + ln * 4);
                *(floatx4*)(obase + (size_t)co * 65536 + rr * 256 + ln * 4) = v;
            }
        }

        s0 += 4;
        if (s0 >= NSLOT) s0 -= NSLOT;
    }
}

// ---------- fallback (proven V2 fp32) if workspace too small ----------
__global__ __launch_bounds__(256) void Conv2d_fallback_kernel(
    const float* __restrict__ x, const float* __restrict__ w,
    const float* __restrict__ bias, float* __restrict__ out) {
    const int tx = threadIdx.x & 15, ty = threadIdx.x >> 4;
    const int ow0 = blockIdx.x * 64 + tx * 4;
    const int oh = blockIdx.y * 16 + ty;
    const int gg = blockIdx.z & 7, n = blockIdx.z >> 3;
    const int co = gg * 16;
    float acc[16][4];
#pragma unroll
    for (int c = 0; c < 16; ++c) {
        const float b = bias[co + c];
#pragma unroll
        for (int p = 0; p < 4; ++p) acc[c][p] = b;
    }
    const float* xn = x + (size_t)n * CIN * HH * WW;
    const float* wb = w + (size_t)co * CIN * 9;
    for (int ci = 0; ci < CIN; ++ci) {
        const float* xc = xn + (size_t)ci * HH * WW;
        float in[3][6];
#pragma unroll
        for (int ky = 0; ky < 3; ++ky) {
            const int iy = oh + ky - 1;
            if ((unsigned)iy < (unsigned)HH) {
                const float* row = xc + iy * WW;
                const float4 v = *(const float4*)(row + ow0);
                in[ky][1] = v.x; in[ky][2] = v.y; in[ky][3] = v.z; in[ky][4] = v.w;
                in[ky][0] = (ow0 > 0) ? row[ow0 - 1] : 0.0f;
                in[ky][5] = (ow0 < WW - 4) ? row[ow0 + 4] : 0.0f;
            } else {
#pragma unroll
                for (int j = 0; j < 6; ++j) in[ky][j] = 0.0f;
            }
        }
        const float* wc2 = wb + ci * 9;
#pragma unroll
        for (int c = 0; c < 16; ++c) {
            const float* wcc = wc2 + (size_t)c * CIN * 9;
#pragma unroll
            for (int ky = 0; ky < 3; ++ky)
#pragma unroll
                for (int kx = 0; kx < 3; ++kx) {
                    const float wv2 = wcc[ky * 3 + kx];
#pragma unroll
                    for (int p = 0; p < 4; ++p) acc[c][p] += in[ky][kx + p] * wv2;
                }
        }
    }
    const size_t hw = (size_t)HH * WW;
    float* ob = out + ((size_t)n * COUT + co) * hw + (size_t)oh * WW + ow0;
#pragma unroll
    for (int c = 0; c < 16; ++c) {
        float4 v;
        v.x = acc[c][0]; v.y = acc[c][1]; v.z = acc[c][2]; v.w = acc[c][3];
        *(float4*)(ob + (size_t)c * hw) = v;
    }
}

extern "C" void kernel_launch(void* const* d_in, const int* in_sizes, int n_in,
                              void* d_out, int out_size, void* d_ws, size_t ws_size,
                              hipStream_t stream) {
    const float* x = (const float*)d_in[0];
    const float* w = (const float*)d_in[1];
    const float* b = (const float*)d_in[2];
    float* out = (float*)d_out;

    const size_t wt_bytes = (size_t)9 * 8 * 128 * 8 * 2;      // 144 KiB

    if (ws_size >= wt_bytes) {
        _Float16* w_t = (_Float16*)d_ws;
        Conv2d_wprep_kernel<<<dim3(288), 256, 0, stream>>>(w, w_t);
        Conv2dManual_77695958385099_kernel<<<dim3(256), 512, 0, stream>>>(
            x, w_t, b, out);
    } else {
        dim3 grid(WW / 64, HH / 16, NB * (COUT / 16));
        Conv2d_fallback_kernel<<<grid, 256, 0, stream>>>(x, w, b, out);
    }
}